// Round 3
// baseline (249.831 us; speedup 1.0000x reference)
//
#include <hip/hip_runtime.h>
#include <math.h>

#define DD   256   // feature dim
#define NN   128   // neighbors
#define NB   572   // drugs (batch)
#define NREL 100   // distinct relation rows
#define KT   32    // k-tile
#define NKT  (DD / KT)

__device__ __forceinline__ float4 ld4(const float* p) {
    return *reinterpret_cast<const float4*>(p);
}

// async global->LDS, 16B per lane: LDS dest = (uniform base) + lane*16
__device__ __forceinline__ void g2lds16(const float* g, float* lds_base) {
    __builtin_amdgcn_global_load_lds(
        (const __attribute__((address_space(1))) void*)g,
        (__attribute__((address_space(3))) void*)lds_base,
        16, 0, 0);
}

// ---------------------------------------------------------------------------
// b2 row-sums (block-independent): b2s[n] = sum_e b2[n,e]
// ---------------------------------------------------------------------------
__global__ void sum_b2(const float* __restrict__ b2, float* __restrict__ b2s)
{
    const int t = threadIdx.x;           // 256
    const int n = t >> 1, h = t & 1;
    const float* p = b2 + n * DD + h * 128;
    float s = 0.f;
    #pragma unroll
    for (int j = 0; j < 32; ++j) {
        float4 v = ld4(&p[j * 4]);
        s += v.x + v.y + v.z + v.w;
    }
    s += __shfl_xor(s, 1, 64);
    if (h == 0) b2s[n] = s;
}

// ---------------------------------------------------------------------------
// Main per-drug kernel.
//  - dedupe relations (<=100 distinct): matmul rows = unique rels only
//  - A_u = (d*rela_u) @ W1[b]   (f32, 8x16 thread tile, 256 threads)
//  - W2[b] row-sums streamed inside the k-loop (collapses second einsum)
//  - logit[n] = relu(A_u[uidx[n]] + b1[n]) . w2sum + b2sum[n]
//  - softmax -> near-one-hot ent gather -> fused linear+relu -> Y
// ---------------------------------------------------------------------------
__global__ __launch_bounds__(256, 2)
void gnn_main(const float* __restrict__ drug_table,
              const float* __restrict__ rela_table,
              const float* __restrict__ ent_table,
              const float* __restrict__ W1,
              const float* __restrict__ b1,
              const float* __restrict__ W2,
              const float* __restrict__ lin_w,
              const float* __restrict__ lin_b,
              const int*   __restrict__ drug_name,
              const int*   __restrict__ adj_tail,
              const int*   __restrict__ adj_relation,
              const float* __restrict__ b2s_g,
              float* __restrict__ Y)
{
    __shared__ float W1_l[KT * DD];    // 32 KB  [k][e]
    __shared__ float DRT_l[KT * NN];   // 16 KB  [k][u], stride 128
    __shared__ float d_l[DD];
    __shared__ float w2s_l[DD];
    __shared__ float b2s_l[NN];
    __shared__ float score_l[NN];
    __shared__ float x_l[2 * DD];
    __shared__ int   rel_l[NN], tail_l[NN], uidx_l[NN];
    __shared__ int   urel_l[NN], head_l[NN], next_l[NN];
    __shared__ int   map_l[NREL];
    __shared__ int   U_l;

    const int b    = blockIdx.x;
    const int tid  = threadIdx.x;
    const int lane = tid & 63;
    const int wv   = tid >> 6;

    // ---- setup + relation dedupe ----
    if (tid < NN) {
        rel_l[tid]  = adj_relation[b * NN + tid];
        tail_l[tid] = adj_tail[b * NN + tid];
        head_l[tid] = -1;
        b2s_l[tid]  = b2s_g[tid];
    }
    if (tid < NREL) map_l[tid] = -1;
    d_l[tid] = drug_table[(size_t)drug_name[b] * DD + tid];
    __syncthreads();
    if (tid < NN) map_l[rel_l[tid]] = 1;   // same-value races benign
    __syncthreads();
    if (tid == 0) {
        int u = 0;
        for (int i = 0; i < NREL; ++i)
            if (map_l[i] >= 0) { map_l[i] = u; urel_l[u] = i; ++u; }
        U_l = u;
    }
    __syncthreads();
    if (tid < NN) {
        int u = map_l[rel_l[tid]];
        uidx_l[tid] = u;
        next_l[tid] = atomicExch(&head_l[u], tid);  // per-u list; order-free
    }
    __syncthreads();

    const int U  = U_l;
    const int RG = (U + 7) >> 3;       // active 8-row groups
    const int tn = tid >> 4;           // row-group 0..15
    const int td = tid & 15;           // col-thread 0..15

    float acc[8][16];
    #pragma unroll
    for (int r = 0; r < 8; ++r)
        #pragma unroll
        for (int c = 0; c < 16; ++c) acc[r][c] = 0.f;

    const float* W1b = W1 + (size_t)b * DD * DD;
    const float* W2b = W2 + (size_t)b * DD * DD;

    const int su  = tid & 127;         // DRT stage: u column
    const int skh = (tid >> 7) * 16;   // k sub-offset 0/16
    const int w2row = tid >> 3;        // 0..31
    const int w2col = (tid & 7) * 32;

    for (int kt = 0; kt < NKT; ++kt) {
        const int k0 = kt * KT;

        // (1) W2 streaming loads (HBM) — issue first
        float4 wbuf[8];
        #pragma unroll
        for (int j = 0; j < 8; ++j)
            wbuf[j] = ld4(&W2b[(size_t)(k0 + w2row) * DD + w2col + j * 4]);

        // (2) W1 k-tile -> LDS, async, linear
        {
            const float* src = W1b + (size_t)k0 * DD;
            #pragma unroll
            for (int i = 0; i < 8; ++i) {
                int seg = wv * 8 + i;              // 32 segs of 256 floats
                g2lds16(src + seg * 256 + lane * 4, &W1_l[seg * 256]);
            }
        }

        // (3) DRT stage: DRT[k][u] = d[k] * rela[urel[u]][k]  (rela: L2)
        if (su < U) {
            const float* rr = rela_table + (size_t)urel_l[su] * DD + k0 + skh;
            float4 v0 = ld4(rr), v1 = ld4(rr + 4), v2 = ld4(rr + 8), v3 = ld4(rr + 12);
            float vv[16] = {v0.x,v0.y,v0.z,v0.w, v1.x,v1.y,v1.z,v1.w,
                            v2.x,v2.y,v2.z,v2.w, v3.x,v3.y,v3.z,v3.w};
            #pragma unroll
            for (int j = 0; j < 16; ++j)
                DRT_l[(skh + j) * NN + su] = d_l[k0 + skh + j] * vv[j];
        } else {
            #pragma unroll
            for (int j = 0; j < 16; ++j)
                DRT_l[(skh + j) * NN + su] = 0.f;
        }
        __syncthreads();   // drains all vmem (incl. lds-loads + wbuf)

        // (4) consume W2 partial sums
        {
            float s = 0.f;
            #pragma unroll
            for (int j = 0; j < 8; ++j)
                s += wbuf[j].x + wbuf[j].y + wbuf[j].z + wbuf[j].w;
            s += __shfl_xor(s, 1, 64);
            s += __shfl_xor(s, 2, 64);
            s += __shfl_xor(s, 4, 64);
            if ((tid & 7) == 0) w2s_l[k0 + w2row] = s;
        }

        // (5) FMA over the k-tile
        if (tn < RG) {
            for (int k = 0; k < KT; ++k) {
                float4 a0 = ld4(&DRT_l[k * NN + tn * 8]);
                float4 a1 = ld4(&DRT_l[k * NN + tn * 8 + 4]);
                float aa[8] = {a0.x,a0.y,a0.z,a0.w, a1.x,a1.y,a1.z,a1.w};
                float ww[16];
                #pragma unroll
                for (int j = 0; j < 4; ++j) {
                    float4 w4 = ld4(&W1_l[k * DD + j * 64 + td * 4]);
                    ww[j*4+0] = w4.x; ww[j*4+1] = w4.y;
                    ww[j*4+2] = w4.z; ww[j*4+3] = w4.w;
                }
                #pragma unroll
                for (int r = 0; r < 8; ++r)
                    #pragma unroll
                    for (int c = 0; c < 16; ++c)
                        acc[r][c] = fmaf(aa[r], ww[c], acc[r][c]);
            }
        }
        __syncthreads();
    }

    // ---- logits via per-u linked lists (acc indices compile-time static) ----
    float wreg[16];
    #pragma unroll
    for (int j = 0; j < 4; ++j) {
        float4 t = ld4(&w2s_l[j * 64 + td * 4]);
        wreg[j*4+0] = t.x; wreg[j*4+1] = t.y; wreg[j*4+2] = t.z; wreg[j*4+3] = t.w;
    }
    #pragma unroll
    for (int r = 0; r < 8; ++r) {
        const int u = tn * 8 + r;
        int n = (u < U) ? head_l[u] : -1;
        while (n >= 0) {
            float s = 0.f;
            #pragma unroll
            for (int j = 0; j < 4; ++j) {
                float4 bv = ld4(&b1[n * DD + j * 64 + td * 4]);
                s += fmaxf(acc[r][j*4+0] + bv.x, 0.f) * wreg[j*4+0];
                s += fmaxf(acc[r][j*4+1] + bv.y, 0.f) * wreg[j*4+1];
                s += fmaxf(acc[r][j*4+2] + bv.z, 0.f) * wreg[j*4+2];
                s += fmaxf(acc[r][j*4+3] + bv.w, 0.f) * wreg[j*4+3];
            }
            #pragma unroll
            for (int m = 8; m >= 1; m >>= 1) s += __shfl_xor(s, m, 16);
            if (td == 0) score_l[n] = s + b2s_l[n];
            n = next_l[n];
        }
    }
    __syncthreads();

    // ---- softmax over 128 logits (wave 0) ----
    if (tid < 64) {
        float l0 = score_l[tid], l1 = score_l[tid + 64];
        float M = fmaxf(l0, l1);
        #pragma unroll
        for (int m = 32; m >= 1; m >>= 1) M = fmaxf(M, __shfl_xor(M, m, 64));
        float e0 = expf(l0 - M), e1 = expf(l1 - M);
        float S = e0 + e1;
        #pragma unroll
        for (int m = 32; m >= 1; m >>= 1) S += __shfl_xor(S, m, 64);
        float inv = 1.f / S;
        score_l[tid]      = e0 * inv;
        score_l[tid + 64] = e1 * inv;
    }
    __syncthreads();

    // ---- sparse ent gather (softmax ~one-hot; skipped mass < 1.3e-7) ----
    float w = 0.f;
    for (int n = 0; n < NN; ++n) {
        float s = score_l[n];
        if (s > 1e-9f)
            w = fmaf(s, ent_table[(size_t)tail_l[n] * DD + tid], w);
    }
    x_l[tid]      = w;
    x_l[DD + tid] = d_l[tid];
    __syncthreads();

    // ---- y[row] = relu(x . lin_w[row,:] + lin_b[row]) ----
    {
        const float* lw = lin_w + (size_t)tid * (2 * DD);
        float dot = 0.f;
        #pragma unroll 8
        for (int k4 = 0; k4 < (2 * DD) / 4; ++k4) {
            float4 xv = ld4(&x_l[k4 * 4]);
            float4 wv4 = ld4(&lw[k4 * 4]);
            dot += xv.x * wv4.x + xv.y * wv4.y + xv.z * wv4.z + xv.w * wv4.w;
        }
        Y[(size_t)b * DD + tid] = fmaxf(dot + lin_b[tid], 0.f);
    }
}

// ---------------------------------------------------------------------------
// BN stats (biased variance) + apply
// ---------------------------------------------------------------------------
__global__ void bn_stats(const float* __restrict__ Y, float* __restrict__ stats)
{
    int d = blockIdx.x, t = threadIdx.x;  // 64 threads
    float s = 0.f, ss = 0.f;
    for (int b = t; b < NB; b += 64) {
        float v = Y[(size_t)b * DD + d];
        s += v; ss += v * v;
    }
    #pragma unroll
    for (int m = 32; m >= 1; m >>= 1) {
        s  += __shfl_xor(s, m, 64);
        ss += __shfl_xor(ss, m, 64);
    }
    if (t == 0) {
        float mean = s * (1.f / NB);
        float var  = ss * (1.f / NB) - mean * mean;
        stats[d]      = mean;
        stats[DD + d] = rsqrtf(var + 1e-5f);
    }
}

__global__ void bn_apply(float* __restrict__ Y, const float* __restrict__ stats,
                         const float* __restrict__ gamma, const float* __restrict__ beta)
{
    int b = blockIdx.x, t = threadIdx.x;
    float mean = stats[t], inv = stats[DD + t];
    float v = Y[(size_t)b * DD + t];
    Y[(size_t)b * DD + t] = gamma[t] * (v - mean) * inv + beta[t];
}

extern "C" void kernel_launch(void* const* d_in, const int* in_sizes, int n_in,
                              void* d_out, int out_size, void* d_ws, size_t ws_size,
                              hipStream_t stream)
{
    const float* drug_table = (const float*)d_in[0];
    const float* rela_table = (const float*)d_in[1];
    const float* ent_table  = (const float*)d_in[2];
    const float* W1         = (const float*)d_in[3];
    const float* b1         = (const float*)d_in[4];
    const float* W2         = (const float*)d_in[5];
    const float* b2         = (const float*)d_in[6];
    const float* lin_w      = (const float*)d_in[7];
    const float* lin_b      = (const float*)d_in[8];
    const float* bn_g       = (const float*)d_in[9];
    const float* bn_b       = (const float*)d_in[10];
    const int*   drug_name  = (const int*)d_in[11];
    const int*   adj_tail   = (const int*)d_in[12];
    const int*   adj_rel    = (const int*)d_in[13];
    float* out = (float*)d_out;

    float* b2s   = (float*)d_ws;       // NN floats
    float* stats = b2s + NN;           // 2*DD floats

    sum_b2<<<1, 256, 0, stream>>>(b2, b2s);
    gnn_main<<<NB, 256, 0, stream>>>(drug_table, rela_table, ent_table,
                                     W1, b1, W2, lin_w, lin_b,
                                     drug_name, adj_tail, adj_rel, b2s, out);
    bn_stats<<<DD, 64, 0, stream>>>(out, stats);
    bn_apply<<<NB, DD, 0, stream>>>(out, stats, bn_g, bn_b);
}

// Round 4
// 220.852 us; speedup vs baseline: 1.1312x; 1.1312x over previous
//
#include <hip/hip_runtime.h>
#include <math.h>

#define DD   256   // feature dim
#define NN   128   // neighbors
#define NB   572   // drugs
#define NREL 100   // distinct relation rows
#define KT   16    // k-tile
#define NKT  (DD / KT)
#define EH   128   // e-half width (each matmul block does half the output cols)

__device__ __forceinline__ float4 ld4(const float* p) {
    return *reinterpret_cast<const float4*>(p);
}

// async global->LDS, 16B/lane: LDS dest = wave-uniform base + lane*16
__device__ __forceinline__ void g2lds16(const float* g, float* lds_base) {
    __builtin_amdgcn_global_load_lds(
        (const __attribute__((address_space(1))) void*)g,
        (__attribute__((address_space(3))) void*)lds_base,
        16, 0, 0);
}

// ---------------------------------------------------------------------------
// Kernel 1: streaming row-sums (collapses the second einsum).
// blocks 0..2*NB-1: half of W2[b]. block 2*NB: b2 row-sums.
// ---------------------------------------------------------------------------
__global__ __launch_bounds__(256)
void sum_rows(const float* __restrict__ W2, const float* __restrict__ b2,
              float* __restrict__ w2s, float* __restrict__ b2s)
{
    const int blk  = blockIdx.x;
    const int tid  = threadIdx.x;
    const int lane = tid & 63;
    const int wv   = tid >> 6;

    if (blk < 2 * NB) {
        const int b = blk >> 1, half = blk & 1;
        const float* src = W2 + (size_t)b * DD * DD + (size_t)half * (DD / 2) * DD;
        float* dst = w2s + (size_t)b * DD + half * (DD / 2);
        for (int r = wv; r < DD / 2; r += 4) {
            float4 v = ld4(&src[r * DD + lane * 4]);
            float s = v.x + v.y + v.z + v.w;
            #pragma unroll
            for (int m = 32; m >= 1; m >>= 1) s += __shfl_xor(s, m, 64);
            if (lane == 0) dst[r] = s;
        }
    } else {
        for (int r = wv; r < NN; r += 4) {
            float4 v = ld4(&b2[r * DD + lane * 4]);
            float s = v.x + v.y + v.z + v.w;
            #pragma unroll
            for (int m = 32; m >= 1; m >>= 1) s += __shfl_xor(s, m, 64);
            if (lane == 0) b2s[r] = s;
        }
    }
}

// ---------------------------------------------------------------------------
// Kernel 2: matmul + partial logits. Block = (drug b, e-half h). 512 threads.
// Dedupe relations (ballot compaction), double-buffered k-loop
// (global_load_lds W1 + ds_write DRT for tile kt+1 overlap FMA on tile kt),
// then partial logit via per-u linked lists:
//   part[b, h*128+n] = sum_{e in half} relu(A[u(n),e] + b1[n,e]) * w2s[b,e]
// ---------------------------------------------------------------------------
__global__ __launch_bounds__(512, 4)
void gnn_mm(const float* __restrict__ drug_table,
            const float* __restrict__ rela_table,
            const float* __restrict__ W1,
            const float* __restrict__ b1,
            const int*   __restrict__ drug_name,
            const int*   __restrict__ adj_relation,
            const float* __restrict__ w2s_g,
            float* __restrict__ part)
{
    __shared__ float W1_l[2][KT * EH];   // 2 x 8 KB
    __shared__ float DRT_l[2][KT * NN];  // 2 x 8 KB
    __shared__ float d_l[DD];
    __shared__ float w2s_l[EH];
    __shared__ int   rel_l[NN], urel_l[NN], head_l[NN], next_l[NN];
    __shared__ int   map_l[NREL];
    __shared__ int   U_l, c0_l;

    const int bid  = blockIdx.x;
    const int b    = bid >> 1, h = bid & 1;
    const int tid  = threadIdx.x;
    const int lane = tid & 63;
    const int wv   = tid >> 6;

    // ---- setup ----
    if (tid < NN) { rel_l[tid] = adj_relation[b * NN + tid]; head_l[tid] = -1; }
    if (tid < NREL) map_l[tid] = -1;
    if (tid < DD)  d_l[tid] = drug_table[(size_t)drug_name[b] * DD + tid];
    if (tid >= DD && tid < DD + EH)
        w2s_l[tid - DD] = w2s_g[(size_t)b * DD + h * EH + (tid - DD)];
    __syncthreads();
    if (tid < NN) map_l[rel_l[tid]] = 1;   // same-value races benign
    __syncthreads();

    // ---- ballot-based compaction of the <=100 marked relations ----
    bool mk = false; int rank = 0, tot = 0;
    if (tid < 128) {
        mk = (tid < NREL) && (map_l[tid] != -1);
        unsigned long long bal = __ballot(mk);
        rank = __popcll(bal & ((1ull << (tid & 63)) - 1));
        tot  = __popcll(bal);
    }
    if (tid < 64) {
        if (mk) { map_l[tid] = rank; urel_l[rank] = tid; }
        if (tid == 0) c0_l = tot;
    }
    __syncthreads();
    if (tid >= 64 && tid < 128) {
        const int base = c0_l;
        if (mk) { map_l[tid] = base + rank; urel_l[base + rank] = tid; }
        if (tid == 64) U_l = base + tot;
    }
    __syncthreads();
    if (tid < NN)
        next_l[tid] = atomicExch(&head_l[map_l[rel_l[tid]]], tid); // order-free
    __syncthreads();

    const int U  = U_l;
    const int RG = (U + 3) >> 2;      // active 4-row groups
    const int tn = tid >> 4;          // 0..31
    const int td = tid & 15;          // 0..15

    float acc[4][8];
    #pragma unroll
    for (int r = 0; r < 4; ++r)
        #pragma unroll
        for (int c = 0; c < 8; ++c) acc[r][c] = 0.f;

    const float* W1b = W1 + (size_t)b * DD * DD;

    const int su  = tid & 127;        // DRT stage: u column
    const int skq = (tid >> 7) * 4;   // k sub-offset 0/4/8/12
    const int f   = wv * 256 + lane * 4;          // W1 stage flat idx
    const int kof = f >> 7, eof = f & 127;

    #define STAGE(buf, kt_)                                                    \
    {                                                                          \
        const int k0_ = (kt_) * KT;                                            \
        g2lds16(W1b + (size_t)(k0_ + kof) * DD + h * EH + eof,                 \
                &W1_l[buf][wv * 256]);                                         \
        if (su < U) {                                                          \
            const float* rr = rela_table + (size_t)urel_l[su] * DD + k0_ + skq;\
            float4 v = ld4(rr);                                                \
            DRT_l[buf][(skq + 0) * NN + su] = d_l[k0_ + skq + 0] * v.x;        \
            DRT_l[buf][(skq + 1) * NN + su] = d_l[k0_ + skq + 1] * v.y;        \
            DRT_l[buf][(skq + 2) * NN + su] = d_l[k0_ + skq + 2] * v.z;        \
            DRT_l[buf][(skq + 3) * NN + su] = d_l[k0_ + skq + 3] * v.w;        \
        } else {                                                               \
            DRT_l[buf][(skq + 0) * NN + su] = 0.f;                             \
            DRT_l[buf][(skq + 1) * NN + su] = 0.f;                             \
            DRT_l[buf][(skq + 2) * NN + su] = 0.f;                             \
            DRT_l[buf][(skq + 3) * NN + su] = 0.f;                             \
        }                                                                      \
    }

    STAGE(0, 0);
    __syncthreads();

    for (int kt = 0; kt < NKT; ++kt) {
        const int cur = kt & 1;
        if (kt + 1 < NKT) STAGE(cur ^ 1, kt + 1);

        if (tn < RG) {
            #pragma unroll 4
            for (int k = 0; k < KT; ++k) {
                float4 a = ld4(&DRT_l[cur][k * NN + tn * 4]);
                float aa[4] = {a.x, a.y, a.z, a.w};
                float4 w0 = ld4(&W1_l[cur][k * EH + td * 4]);
                float4 w1 = ld4(&W1_l[cur][k * EH + 64 + td * 4]);
                float ww[8] = {w0.x, w0.y, w0.z, w0.w, w1.x, w1.y, w1.z, w1.w};
                #pragma unroll
                for (int r = 0; r < 4; ++r)
                    #pragma unroll
                    for (int c = 0; c < 8; ++c)
                        acc[r][c] = fmaf(aa[r], ww[c], acc[r][c]);
            }
        }
        __syncthreads();
    }
    #undef STAGE

    // ---- partial logits via per-u linked lists ----
    float wreg[8];
    {
        float4 t0 = ld4(&w2s_l[td * 4]);
        float4 t1 = ld4(&w2s_l[64 + td * 4]);
        wreg[0]=t0.x; wreg[1]=t0.y; wreg[2]=t0.z; wreg[3]=t0.w;
        wreg[4]=t1.x; wreg[5]=t1.y; wreg[6]=t1.z; wreg[7]=t1.w;
    }
    #pragma unroll
    for (int r = 0; r < 4; ++r) {
        const int u = tn * 4 + r;
        int n = (u < U) ? head_l[u] : -1;
        while (n >= 0) {
            const float* bp = b1 + (size_t)n * DD + h * EH;
            float4 b0 = ld4(&bp[td * 4]);
            float4 b1v = ld4(&bp[64 + td * 4]);
            float s = fmaxf(acc[r][0] + b0.x, 0.f) * wreg[0]
                    + fmaxf(acc[r][1] + b0.y, 0.f) * wreg[1]
                    + fmaxf(acc[r][2] + b0.z, 0.f) * wreg[2]
                    + fmaxf(acc[r][3] + b0.w, 0.f) * wreg[3]
                    + fmaxf(acc[r][4] + b1v.x, 0.f) * wreg[4]
                    + fmaxf(acc[r][5] + b1v.y, 0.f) * wreg[5]
                    + fmaxf(acc[r][6] + b1v.z, 0.f) * wreg[6]
                    + fmaxf(acc[r][7] + b1v.w, 0.f) * wreg[7];
            #pragma unroll
            for (int m = 8; m >= 1; m >>= 1) s += __shfl_xor(s, m, 16);
            if (td == 0) part[(size_t)b * 256 + h * NN + n] = s;
            n = next_l[n];
        }
    }
}

// ---------------------------------------------------------------------------
// Kernel 3: finish per drug — combine partial logits, softmax, sparse ent
// gather, fused linear+relu. Writes pre-BN y.
// ---------------------------------------------------------------------------
__global__ __launch_bounds__(256)
void gnn_fin(const float* __restrict__ drug_table,
             const float* __restrict__ ent_table,
             const float* __restrict__ lin_w,
             const float* __restrict__ lin_b,
             const int*   __restrict__ drug_name,
             const int*   __restrict__ adj_tail,
             const float* __restrict__ part,
             const float* __restrict__ b2s_g,
             float* __restrict__ Y)
{
    __shared__ float score_l[NN];
    __shared__ float x_l[2 * DD];
    __shared__ int   tail_l[NN];

    const int b = blockIdx.x, tid = threadIdx.x;

    if (tid < NN) {
        tail_l[tid]  = adj_tail[b * NN + tid];
        score_l[tid] = part[(size_t)b * 256 + tid]
                     + part[(size_t)b * 256 + NN + tid] + b2s_g[tid];
    }
    x_l[DD + tid] = drug_table[(size_t)drug_name[b] * DD + tid];
    __syncthreads();

    if (tid < 64) {
        float l0 = score_l[tid], l1 = score_l[tid + 64];
        float M = fmaxf(l0, l1);
        #pragma unroll
        for (int m = 32; m >= 1; m >>= 1) M = fmaxf(M, __shfl_xor(M, m, 64));
        float e0 = expf(l0 - M), e1 = expf(l1 - M);
        float S = e0 + e1;
        #pragma unroll
        for (int m = 32; m >= 1; m >>= 1) S += __shfl_xor(S, m, 64);
        float inv = 1.f / S;
        score_l[tid]      = e0 * inv;
        score_l[tid + 64] = e1 * inv;
    }
    __syncthreads();

    // sparse gather (softmax ~one-hot; skipped mass < 1.3e-7)
    float w = 0.f;
    for (int n = 0; n < NN; ++n) {
        float s = score_l[n];
        if (s > 1e-9f)
            w = fmaf(s, ent_table[(size_t)tail_l[n] * DD + tid], w);
    }
    x_l[tid] = w;
    __syncthreads();

    const float* lw = lin_w + (size_t)tid * (2 * DD);
    float dot = 0.f;
    #pragma unroll 8
    for (int k4 = 0; k4 < (2 * DD) / 4; ++k4) {
        float4 xv = ld4(&x_l[k4 * 4]);
        float4 wv4 = ld4(&lw[k4 * 4]);
        dot += xv.x * wv4.x + xv.y * wv4.y + xv.z * wv4.z + xv.w * wv4.w;
    }
    Y[(size_t)b * DD + tid] = fmaxf(dot + lin_b[tid], 0.f);
}

// ---------------------------------------------------------------------------
// BN stats (biased variance) + apply
// ---------------------------------------------------------------------------
__global__ void bn_stats(const float* __restrict__ Y, float* __restrict__ stats)
{
    int d = blockIdx.x, t = threadIdx.x;  // 64 threads
    float s = 0.f, ss = 0.f;
    for (int b = t; b < NB; b += 64) {
        float v = Y[(size_t)b * DD + d];
        s += v; ss += v * v;
    }
    #pragma unroll
    for (int m = 32; m >= 1; m >>= 1) {
        s  += __shfl_xor(s, m, 64);
        ss += __shfl_xor(ss, m, 64);
    }
    if (t == 0) {
        float mean = s * (1.f / NB);
        float var  = ss * (1.f / NB) - mean * mean;
        stats[d]      = mean;
        stats[DD + d] = rsqrtf(var + 1e-5f);
    }
}

__global__ void bn_apply(float* __restrict__ Y, const float* __restrict__ stats,
                         const float* __restrict__ gamma, const float* __restrict__ beta)
{
    int b = blockIdx.x, t = threadIdx.x;
    float mean = stats[t], inv = stats[DD + t];
    float v = Y[(size_t)b * DD + t];
    Y[(size_t)b * DD + t] = gamma[t] * (v - mean) * inv + beta[t];
}

extern "C" void kernel_launch(void* const* d_in, const int* in_sizes, int n_in,
                              void* d_out, int out_size, void* d_ws, size_t ws_size,
                              hipStream_t stream)
{
    const float* drug_table = (const float*)d_in[0];
    const float* rela_table = (const float*)d_in[1];
    const float* ent_table  = (const float*)d_in[2];
    const float* W1         = (const float*)d_in[3];
    const float* b1         = (const float*)d_in[4];
    const float* W2         = (const float*)d_in[5];
    const float* b2         = (const float*)d_in[6];
    const float* lin_w      = (const float*)d_in[7];
    const float* lin_b      = (const float*)d_in[8];
    const float* bn_g       = (const float*)d_in[9];
    const float* bn_b       = (const float*)d_in[10];
    const int*   drug_name  = (const int*)d_in[11];
    const int*   adj_tail   = (const int*)d_in[12];
    const int*   adj_rel    = (const int*)d_in[13];
    float* out = (float*)d_out;

    float* w2s   = (float*)d_ws;                   // NB*DD
    float* b2s   = w2s + (size_t)NB * DD;          // NN
    float* part  = b2s + NN;                       // NB*256
    float* stats = part + (size_t)NB * 256;        // 2*DD

    sum_rows<<<2 * NB + 1, 256, 0, stream>>>(W2, b2, w2s, b2s);
    gnn_mm<<<2 * NB, 512, 0, stream>>>(drug_table, rela_table, W1, b1,
                                       drug_name, adj_rel, w2s, part);
    gnn_fin<<<NB, 256, 0, stream>>>(drug_table, ent_table, lin_w, lin_b,
                                    drug_name, adj_tail, part, b2s, out);
    bn_stats<<<DD, 64, 0, stream>>>(out, stats);
    bn_apply<<<NB, DD, 0, stream>>>(out, stats, bn_g, bn_b);
}

// Round 5
// 209.085 us; speedup vs baseline: 1.1949x; 1.0563x over previous
//
#include <hip/hip_runtime.h>
#include <math.h>

#define DD   256   // feature dim
#define NN   128   // neighbors
#define NB   572   // drugs
#define NREL 100   // distinct relation rows
#define KT   16    // k-tile
#define NKT  (DD / KT)
#define EH   128   // e-half width per mm block
#define LDRUGS 8   // drugs per linear block

__device__ __forceinline__ float4 ld4(const float* p) {
    return *reinterpret_cast<const float4*>(p);
}

// async global->LDS, 16B/lane: LDS dest = wave-uniform base + lane*16
__device__ __forceinline__ void g2lds16(const float* g, float* lds_base) {
    __builtin_amdgcn_global_load_lds(
        (const __attribute__((address_space(1))) void*)g,
        (__attribute__((address_space(3))) void*)lds_base,
        16, 0, 0);
}

// ---------------------------------------------------------------------------
// Kernel 1: streaming row-sums (collapses the second einsum).
// blocks 0..2*NB-1: half of W2[b]. block 2*NB: b2 row-sums.
// ---------------------------------------------------------------------------
__global__ __launch_bounds__(256)
void sum_rows(const float* __restrict__ W2, const float* __restrict__ b2,
              float* __restrict__ w2s, float* __restrict__ b2s)
{
    const int blk  = blockIdx.x;
    const int tid  = threadIdx.x;
    const int lane = tid & 63;
    const int wv   = tid >> 6;

    if (blk < 2 * NB) {
        const int b = blk >> 1, half = blk & 1;
        const float* src = W2 + (size_t)b * DD * DD + (size_t)half * (DD / 2) * DD;
        float* dst = w2s + (size_t)b * DD + half * (DD / 2);
        for (int r = wv; r < DD / 2; r += 4) {
            float4 v = ld4(&src[r * DD + lane * 4]);
            float s = v.x + v.y + v.z + v.w;
            #pragma unroll
            for (int m = 32; m >= 1; m >>= 1) s += __shfl_xor(s, m, 64);
            if (lane == 0) dst[r] = s;
        }
    } else {
        for (int r = wv; r < NN; r += 4) {
            float4 v = ld4(&b2[r * DD + lane * 4]);
            float s = v.x + v.y + v.z + v.w;
            #pragma unroll
            for (int m = 32; m >= 1; m >>= 1) s += __shfl_xor(s, m, 64);
            if (lane == 0) b2s[r] = s;
        }
    }
}

// ---------------------------------------------------------------------------
// Kernel 2: matmul + partial logits. Block = (drug b, e-half h). 512 threads.
// Relations deduped (ballot compaction); rows assigned CYCLICALLY to the 32
// row-groups (tn, tn+32, tn+64, tn+96) so all waves stay FMA-active for any U.
// Double-buffered k-loop: global_load_lds W1 + ds_write DRT for tile kt+1
// overlap FMA on tile kt. Emits partial logits:
//   part[b, h*128+n] = sum_{e in half} relu(A[u(n),e] + b1[n,e]) * w2s[b,e]
// ---------------------------------------------------------------------------
__global__ __launch_bounds__(512, 6)
void gnn_mm(const float* __restrict__ drug_table,
            const float* __restrict__ rela_table,
            const float* __restrict__ W1,
            const float* __restrict__ b1,
            const int*   __restrict__ drug_name,
            const int*   __restrict__ adj_relation,
            const float* __restrict__ w2s_g,
            float* __restrict__ part)
{
    __shared__ float W1_l[2][KT * EH];   // 2 x 8 KB
    __shared__ float DRT_l[2][KT * NN];  // 2 x 8 KB
    __shared__ float d_l[DD];
    __shared__ int   rel_l[NN], urel_l[NN], head_l[NN], next_l[NN];
    __shared__ int   map_l[NREL];
    __shared__ int   U_l, c0_l;

    const int bid  = blockIdx.x;
    const int b    = bid >> 1, h = bid & 1;
    const int tid  = threadIdx.x;
    const int lane = tid & 63;
    const int wv   = tid >> 6;

    // ---- setup ----
    if (tid < NN) { rel_l[tid] = adj_relation[b * NN + tid]; head_l[tid] = -1; }
    if (tid < NREL) map_l[tid] = -1;
    if (tid < DD)  d_l[tid] = drug_table[(size_t)drug_name[b] * DD + tid];
    __syncthreads();
    if (tid < NN) map_l[rel_l[tid]] = 1;   // same-value races benign
    __syncthreads();

    // ---- ballot-based compaction of the <=100 marked relations ----
    bool mk = false; int rank = 0, tot = 0;
    if (tid < 128) {
        mk = (tid < NREL) && (map_l[tid] != -1);
        unsigned long long bal = __ballot(mk);
        rank = __popcll(bal & ((1ull << (tid & 63)) - 1));
        tot  = __popcll(bal);
    }
    if (tid < 64) {
        if (mk) { map_l[tid] = rank; urel_l[rank] = tid; }
        if (tid == 0) c0_l = tot;
    }
    __syncthreads();
    if (tid >= 64 && tid < 128) {
        const int base = c0_l;
        if (mk) { map_l[tid] = base + rank; urel_l[base + rank] = tid; }
        if (tid == 64) U_l = base + tot;
    }
    __syncthreads();
    if (tid < NN)
        next_l[tid] = atomicExch(&head_l[map_l[rel_l[tid]]], tid); // order-free
    __syncthreads();

    const int U  = U_l;
    const int tn = tid >> 4;          // row-group 0..31
    const int td = tid & 15;          // col-thread 0..15

    const bool a0 = (tn      < U);
    const bool a1 = (tn + 32 < U);
    const bool a2 = (tn + 64 < U);
    const bool a3 = (tn + 96 < U);

    float acc[4][8];
    #pragma unroll
    for (int r = 0; r < 4; ++r)
        #pragma unroll
        for (int c = 0; c < 8; ++c) acc[r][c] = 0.f;

    const float* W1b = W1 + (size_t)b * DD * DD;

    const int su  = tid & 127;        // DRT stage: u column
    const int skq = (tid >> 7) * 4;   // k sub-offset 0/4/8/12
    const int f   = wv * 256 + lane * 4;          // W1 stage flat idx
    const int kof = f >> 7, eof = f & 127;

    #define STAGE(buf, kt_)                                                    \
    {                                                                          \
        const int k0_ = (kt_) * KT;                                            \
        g2lds16(W1b + (size_t)(k0_ + kof) * DD + h * EH + eof,                 \
                &W1_l[buf][wv * 256]);                                         \
        if (su < U) {                                                          \
            const float* rr = rela_table + (size_t)urel_l[su] * DD + k0_ + skq;\
            float4 v = ld4(rr);                                                \
            DRT_l[buf][(skq + 0) * NN + su] = d_l[k0_ + skq + 0] * v.x;        \
            DRT_l[buf][(skq + 1) * NN + su] = d_l[k0_ + skq + 1] * v.y;        \
            DRT_l[buf][(skq + 2) * NN + su] = d_l[k0_ + skq + 2] * v.z;        \
            DRT_l[buf][(skq + 3) * NN + su] = d_l[k0_ + skq + 3] * v.w;        \
        }                                                                      \
    }

    STAGE(0, 0);
    __syncthreads();

    #define FMA8(j, a)                                                         \
        { acc[j][0] = fmaf(a, ww[0], acc[j][0]);                               \
          acc[j][1] = fmaf(a, ww[1], acc[j][1]);                               \
          acc[j][2] = fmaf(a, ww[2], acc[j][2]);                               \
          acc[j][3] = fmaf(a, ww[3], acc[j][3]);                               \
          acc[j][4] = fmaf(a, ww[4], acc[j][4]);                               \
          acc[j][5] = fmaf(a, ww[5], acc[j][5]);                               \
          acc[j][6] = fmaf(a, ww[6], acc[j][6]);                               \
          acc[j][7] = fmaf(a, ww[7], acc[j][7]); }

    for (int kt = 0; kt < NKT; ++kt) {
        const int cur = kt & 1;
        if (kt + 1 < NKT) STAGE(cur ^ 1, kt + 1);

        #pragma unroll 2
        for (int k = 0; k < KT; ++k) {
            float4 w0 = ld4(&W1_l[cur][k * EH + td * 4]);
            float4 w1 = ld4(&W1_l[cur][k * EH + 64 + td * 4]);
            float ww[8] = {w0.x, w0.y, w0.z, w0.w, w1.x, w1.y, w1.z, w1.w};
            if (a0) { float a = DRT_l[cur][k * NN + tn];      FMA8(0, a); }
            if (a1) { float a = DRT_l[cur][k * NN + tn + 32]; FMA8(1, a); }
            if (a2) { float a = DRT_l[cur][k * NN + tn + 64]; FMA8(2, a); }
            if (a3) { float a = DRT_l[cur][k * NN + tn + 96]; FMA8(3, a); }
        }
        __syncthreads();
    }
    #undef STAGE
    #undef FMA8

    // ---- partial logits via per-u linked lists (static acc indexing) ----
    float wreg[8];
    {
        float4 t0 = ld4(&w2s_g[(size_t)b * DD + h * EH + td * 4]);
        float4 t1 = ld4(&w2s_g[(size_t)b * DD + h * EH + 64 + td * 4]);
        wreg[0]=t0.x; wreg[1]=t0.y; wreg[2]=t0.z; wreg[3]=t0.w;
        wreg[4]=t1.x; wreg[5]=t1.y; wreg[6]=t1.z; wreg[7]=t1.w;
    }
    #pragma unroll
    for (int r = 0; r < 4; ++r) {
        const int u = tn + 32 * r;
        int n = (u < U) ? head_l[u] : -1;
        while (n >= 0) {
            const float* bp = b1 + (size_t)n * DD + h * EH;
            float4 b0 = ld4(&bp[td * 4]);
            float4 b1v = ld4(&bp[64 + td * 4]);
            float s = fmaxf(acc[r][0] + b0.x,  0.f) * wreg[0]
                    + fmaxf(acc[r][1] + b0.y,  0.f) * wreg[1]
                    + fmaxf(acc[r][2] + b0.z,  0.f) * wreg[2]
                    + fmaxf(acc[r][3] + b0.w,  0.f) * wreg[3]
                    + fmaxf(acc[r][4] + b1v.x, 0.f) * wreg[4]
                    + fmaxf(acc[r][5] + b1v.y, 0.f) * wreg[5]
                    + fmaxf(acc[r][6] + b1v.z, 0.f) * wreg[6]
                    + fmaxf(acc[r][7] + b1v.w, 0.f) * wreg[7];
            #pragma unroll
            for (int m = 8; m >= 1; m >>= 1) s += __shfl_xor(s, m, 16);
            if (td == 0) part[(size_t)b * 256 + h * NN + n] = s;
            n = next_l[n];
        }
    }
}

// ---------------------------------------------------------------------------
// Kernel 3: per drug — combine partial logits, softmax, sparse ent gather,
// build x = [w_ent | d] in workspace.
// ---------------------------------------------------------------------------
__global__ __launch_bounds__(256)
void gnn_gather(const float* __restrict__ drug_table,
                const float* __restrict__ ent_table,
                const int*   __restrict__ drug_name,
                const int*   __restrict__ adj_tail,
                const float* __restrict__ part,
                const float* __restrict__ b2s_g,
                float* __restrict__ xbuf)
{
    __shared__ float score_l[NN];
    __shared__ int   tail_l[NN];

    const int b = blockIdx.x, tid = threadIdx.x;

    if (tid < NN) {
        tail_l[tid]  = adj_tail[b * NN + tid];
        score_l[tid] = part[(size_t)b * 256 + tid]
                     + part[(size_t)b * 256 + NN + tid] + b2s_g[tid];
    }
    __syncthreads();

    if (tid < 64) {
        float l0 = score_l[tid], l1 = score_l[tid + 64];
        float M = fmaxf(l0, l1);
        #pragma unroll
        for (int m = 32; m >= 1; m >>= 1) M = fmaxf(M, __shfl_xor(M, m, 64));
        float e0 = expf(l0 - M), e1 = expf(l1 - M);
        float S = e0 + e1;
        #pragma unroll
        for (int m = 32; m >= 1; m >>= 1) S += __shfl_xor(S, m, 64);
        float inv = 1.f / S;
        score_l[tid]      = e0 * inv;
        score_l[tid + 64] = e1 * inv;
    }
    __syncthreads();

    // sparse gather (softmax ~one-hot; skipped mass < 1.3e-7)
    float w = 0.f;
    for (int n = 0; n < NN; ++n) {
        float s = score_l[n];
        if (s > 1e-9f)
            w = fmaf(s, ent_table[(size_t)tail_l[n] * DD + tid], w);
    }
    xbuf[(size_t)b * 512 + tid]       = w;
    xbuf[(size_t)b * 512 + 256 + tid] = drug_table[(size_t)drug_name[b] * DD + tid];
}

// ---------------------------------------------------------------------------
// Kernel 4: batched linear — LDRUGS drugs per block amortize lin_w reads.
// y[b,row] = relu(x[b] . lin_w[row,:] + lin_b[row])
// ---------------------------------------------------------------------------
__global__ __launch_bounds__(256)
void gnn_lin(const float* __restrict__ lin_w,
             const float* __restrict__ lin_b,
             const float* __restrict__ xbuf,
             float* __restrict__ Y)
{
    __shared__ float x_l[LDRUGS * 512];   // 16 KB

    const int g = blockIdx.x, tid = threadIdx.x;
    const int b0 = g * LDRUGS;

    #pragma unroll
    for (int i = 0; i < LDRUGS * 2; ++i) {
        int f = tid + i * 256;
        *reinterpret_cast<float4*>(&x_l[f * 4]) = ld4(&xbuf[(size_t)b0 * 512 + f * 4]);
    }
    __syncthreads();

    const float* lw = lin_w + (size_t)tid * 512;
    float dot[LDRUGS];
    #pragma unroll
    for (int d = 0; d < LDRUGS; ++d) dot[d] = 0.f;

    for (int k4 = 0; k4 < 128; ++k4) {
        float4 wv = ld4(&lw[k4 * 4]);
        #pragma unroll
        for (int d = 0; d < LDRUGS; ++d) {
            float4 xv = ld4(&x_l[d * 512 + k4 * 4]);
            dot[d] += wv.x * xv.x + wv.y * xv.y + wv.z * xv.z + wv.w * xv.w;
        }
    }

    const float bb = lin_b[tid];
    #pragma unroll
    for (int d = 0; d < LDRUGS; ++d) {
        if (b0 + d < NB)
            Y[(size_t)(b0 + d) * DD + tid] = fmaxf(dot[d] + bb, 0.f);
    }
}

// ---------------------------------------------------------------------------
// BN stats (biased variance) + apply
// ---------------------------------------------------------------------------
__global__ void bn_stats(const float* __restrict__ Y, float* __restrict__ stats)
{
    int d = blockIdx.x, t = threadIdx.x;  // 64 threads
    float s = 0.f, ss = 0.f;
    for (int b = t; b < NB; b += 64) {
        float v = Y[(size_t)b * DD + d];
        s += v; ss += v * v;
    }
    #pragma unroll
    for (int m = 32; m >= 1; m >>= 1) {
        s  += __shfl_xor(s, m, 64);
        ss += __shfl_xor(ss, m, 64);
    }
    if (t == 0) {
        float mean = s * (1.f / NB);
        float var  = ss * (1.f / NB) - mean * mean;
        stats[d]      = mean;
        stats[DD + d] = rsqrtf(var + 1e-5f);
    }
}

__global__ void bn_apply(float* __restrict__ Y, const float* __restrict__ stats,
                         const float* __restrict__ gamma, const float* __restrict__ beta)
{
    int b = blockIdx.x, t = threadIdx.x;
    float mean = stats[t], inv = stats[DD + t];
    float v = Y[(size_t)b * DD + t];
    Y[(size_t)b * DD + t] = gamma[t] * (v - mean) * inv + beta[t];
}

extern "C" void kernel_launch(void* const* d_in, const int* in_sizes, int n_in,
                              void* d_out, int out_size, void* d_ws, size_t ws_size,
                              hipStream_t stream)
{
    const float* drug_table = (const float*)d_in[0];
    const float* rela_table = (const float*)d_in[1];
    const float* ent_table  = (const float*)d_in[2];
    const float* W1         = (const float*)d_in[3];
    const float* b1         = (const float*)d_in[4];
    const float* W2         = (const float*)d_in[5];
    const float* b2         = (const float*)d_in[6];
    const float* lin_w      = (const float*)d_in[7];
    const float* lin_b      = (const float*)d_in[8];
    const float* bn_g       = (const float*)d_in[9];
    const float* bn_b       = (const float*)d_in[10];
    const int*   drug_name  = (const int*)d_in[11];
    const int*   adj_tail   = (const int*)d_in[12];
    const int*   adj_rel    = (const int*)d_in[13];
    float* out = (float*)d_out;

    const int NBP = ((NB + LDRUGS - 1) / LDRUGS) * LDRUGS;   // 576
    float* w2s   = (float*)d_ws;                     // NB*DD
    float* b2s   = w2s + (size_t)NB * DD;            // NN
    float* part  = b2s + NN;                         // NB*256
    float* xbuf  = part + (size_t)NB * 256;          // NBP*512
    float* stats = xbuf + (size_t)NBP * 512;         // 2*DD

    sum_rows<<<2 * NB + 1, 256, 0, stream>>>(W2, b2, w2s, b2s);
    gnn_mm<<<2 * NB, 512, 0, stream>>>(drug_table, rela_table, W1, b1,
                                       drug_name, adj_rel, w2s, part);
    gnn_gather<<<NB, 256, 0, stream>>>(drug_table, ent_table, drug_name,
                                       adj_tail, part, b2s, xbuf);
    gnn_lin<<<NBP / LDRUGS, 256, 0, stream>>>(lin_w, lin_b, xbuf, out);
    bn_stats<<<DD, 64, 0, stream>>>(out, stats);
    bn_apply<<<NB, DD, 0, stream>>>(out, stats, bn_g, bn_b);
}